// Round 1
// 453.944 us; speedup vs baseline: 1.0732x; 1.0732x over previous
//
#include <hip/hip_runtime.h>
#include <cstdint>
#include <cstddef>

#define N_NODES 50000
#define N_EDGES 800000
#define F_IN    512
#define H_DIM   128
#define C_OUT   40
#define TOT_E   (N_EDGES + N_NODES)
#define KTOT    640             // h | u1 | u2 | u3 | u4
#define NPAD    48              // 40 cols padded to 3 MFMA tiles

typedef __attribute__((ext_vector_type(8))) __bf16 bf16x8;
typedef __attribute__((ext_vector_type(4))) float f32x4;

__device__ __forceinline__ unsigned short bf16_rne(float f) {
  unsigned int u = __float_as_uint(f);
  u += 0x7fffu + ((u >> 16) & 1u);
  return (unsigned short)(u >> 16);
}
__device__ __forceinline__ float bf16_lo_f(unsigned int u) { return __uint_as_float(u << 16); }
__device__ __forceinline__ float bf16_hi_f(unsigned int u) { return __uint_as_float(u & 0xffff0000u); }

// async global->LDS, 16B per lane; dest must be linear (base + lane*16)
#define GLOAD_LDS16(gp, lp)                                                        \
  __builtin_amdgcn_global_load_lds(                                                \
      (const __attribute__((address_space(1))) void*)(gp),                         \
      (__attribute__((address_space(3))) void*)(lp), 16, 0, 0)

// ----------------------------- setup kernels -------------------------------
// Single u64 atomic per edge: bits [40..63] = count, [0..39] = 2^-24 fixed-pt
// weighted degree. Returned old count = slot of edge in its dst bucket.

__global__ void edge_pass1_k(const int* __restrict__ dst, const float* __restrict__ ew,
                             unsigned long long* __restrict__ acc,
                             int* __restrict__ pos, int e) {
  int i = blockIdx.x * blockDim.x + threadIdx.x;
  if (i < e) {
    int d = dst[i];
    unsigned long long v = (1ull << 40) |
        (unsigned long long)(ew[i] * 16777216.0f + 0.5f);
    unsigned long long old = atomicAdd(&acc[d], v);
    pos[i] = (int)(old >> 40);
  }
}

__global__ void node_pass_k(const unsigned long long* __restrict__ acc,
                            float* __restrict__ dinv, int* __restrict__ cnt, int n) {
  int i = blockIdx.x * blockDim.x + threadIdx.x;
  if (i < n) {
    unsigned long long a = acc[i];
    double dfix = (double)(a & 0xFFFFFFFFFFull);
    float deg = (float)(dfix * (1.0 / 16777216.0) + 1.0);   // +1 self-loop
    dinv[i] = rsqrtf(deg);
    cnt[i] = (int)(a >> 40) + 1;                            // +1 self-loop
  }
}

__global__ __launch_bounds__(256) void block_reduce_k(const int* __restrict__ cnt,
                                                      int* bsum, int n) {
  __shared__ int s[256];
  int t = threadIdx.x;
  int i = blockIdx.x * 256 + t;
  s[t] = (i < n) ? cnt[i] : 0;
  __syncthreads();
  for (int off = 128; off; off >>= 1) {
    if (t < off) s[t] += s[t + off];
    __syncthreads();
  }
  if (t == 0) bsum[blockIdx.x] = s[0];
}

__global__ __launch_bounds__(256) void scan_bsums_k(int* bsum, int nb) {
  __shared__ int s[256];
  int t = threadIdx.x;
  s[t] = (t < nb) ? bsum[t] : 0;
  __syncthreads();
  for (int off = 1; off < 256; off <<= 1) {
    int v = (t >= off) ? s[t - off] : 0;
    __syncthreads();
    s[t] += v;
    __syncthreads();
  }
  if (t < nb) bsum[t] = (t == 0) ? 0 : s[t - 1];
}

__global__ __launch_bounds__(256) void scan_write_k(const int* __restrict__ cnt,
                                                    const int* __restrict__ bsum,
                                                    int* row_ptr, int n) {
  __shared__ int s[256];
  int t = threadIdx.x;
  int i = blockIdx.x * 256 + t;
  int c = (i < n) ? cnt[i] : 0;
  s[t] = c;
  __syncthreads();
  for (int off = 1; off < 256; off <<= 1) {
    int v = (t >= off) ? s[t - off] : 0;
    __syncthreads();
    s[t] += v;
    __syncthreads();
  }
  int ex = bsum[blockIdx.x] + ((t == 0) ? 0 : s[t - 1]);
  if (i < n) row_ptr[i] = ex;
  if (i == n - 1) row_ptr[n] = ex + c;
}

__global__ void scatter2_k(const int* __restrict__ src, const int* __restrict__ dst,
                           const float* __restrict__ ew, const int* __restrict__ pos,
                           const float* __restrict__ dinv, const int* __restrict__ rowp,
                           int2* __restrict__ csr, int e, int n) {
  int i = blockIdx.x * blockDim.x + threadIdx.x;
  if (i < e) {
    int s = src[i], d = dst[i];
    float w = dinv[s] * ew[i] * dinv[d];
    csr[rowp[d] + pos[i]] = make_int2(s, __float_as_int(w));
  } else if (i < e + n) {
    int v = i - e;
    float di = dinv[v];
    csr[rowp[v + 1] - 1] = make_int2(v, __float_as_int(di * di));  // self-loop last
  }
}

// ------------------- weight transpose+cast: Wt[n][k] = bf16(W[k][n]) -------
__global__ void wcast_k(const float* __restrict__ W, unsigned short* __restrict__ Wt,
                        int K, int total) {
  int i = blockIdx.x * 256 + threadIdx.x;
  if (i >= total) return;
  int per = K * 128;
  int b = i / per;
  int rem = i - b * per;
  int k = rem >> 7, nn = rem & 127;
  Wt[(size_t)b * per + (size_t)nn * K + k] = bf16_rne(W[i]);
}

// ---- weight-chain precompute: P slices [KTOT x 48] bf16 + rank-1 rows -----
// Column-parallel: grid (10, 4). blockIdx.y = branch b (j=b+1), blockIdx.x =
// column group (4 of 40 cols). Each block evolves a 128x4 slice S <- W_k * S.
__global__ __launch_bounds__(256) void chains_k(
    const float* __restrict__ W_gcn, const float* __restrict__ b_gcn,
    const float* __restrict__ W_out, const float* __restrict__ b_out,
    unsigned short* __restrict__ Pbf, float* __restrict__ rv) {
  __shared__ float T0[128 * 4];
  __shared__ float T1[128 * 4];
  const int b = blockIdx.y;          // 0..3
  const int j = b + 1;
  const int c0 = blockIdx.x * 4;     // col group base
  const int ks_all[4][4] = {{0, -1, -1, -1}, {1, 2, -1, -1}, {3, 4, 5, -1}, {6, 7, 8, 9}};
  const int t = threadIdx.x;
  const int lane = t & 63;
  const int wv = t >> 6;             // wave 0..3

  for (int idx = t; idx < 512; idx += 256) {
    int r = idx >> 2, c = idx & 3;
    T0[idx] = W_out[(size_t)(j * 128 + r) * 40 + c0 + c];
  }
  __syncthreads();
  float* Tc = T0;
  float* Tn = T1;
  for (int step = 0; step < j; ++step) {
    int kw = ks_all[b][j - 1 - step];
    {
      float s = b_gcn[kw * 128 + lane] * Tc[lane * 4 + wv] +
                b_gcn[kw * 128 + 64 + lane] * Tc[(64 + lane) * 4 + wv];
      for (int o = 32; o; o >>= 1) s += __shfl_down(s, o);
      if (lane == 0) atomicAdd(&rv[step * 40 + c0 + wv], s);
    }
    const float* W = W_gcn + (size_t)kw * 128 * 128;
    int r = t & 127;
    int ch = (t >> 7) << 1;          // 0 or 2
    float a0 = 0.f, a1 = 0.f;
    for (int k = 0; k < 128; k += 4) {
      float4 w4 = *(const float4*)&W[(size_t)r * 128 + k];
      a0 += w4.x * Tc[(k + 0) * 4 + ch] + w4.y * Tc[(k + 1) * 4 + ch] +
            w4.z * Tc[(k + 2) * 4 + ch] + w4.w * Tc[(k + 3) * 4 + ch];
      a1 += w4.x * Tc[(k + 0) * 4 + ch + 1] + w4.y * Tc[(k + 1) * 4 + ch + 1] +
            w4.z * Tc[(k + 2) * 4 + ch + 1] + w4.w * Tc[(k + 3) * 4 + ch + 1];
    }
    Tn[r * 4 + ch] = a0;
    Tn[r * 4 + ch + 1] = a1;
    __syncthreads();
    float* tmp = Tc; Tc = Tn; Tn = tmp;
  }
  for (int idx = t; idx < 512; idx += 256) {
    int r = idx >> 2, c = idx & 3;
    Pbf[(size_t)(c0 + c) * KTOT + j * 128 + r] = bf16_rne(Tc[idx]);
  }
  if (b == 0) {
    for (int idx = t; idx < 512; idx += 256) {
      int r = idx >> 2, c = idx & 3;
      Pbf[(size_t)(c0 + c) * KTOT + r] = bf16_rne(W_out[(size_t)r * 40 + c0 + c]);
    }
    if (blockIdx.x == 0 && t < 40) atomicAdd(&rv[t], b_out[t]);   // row_1 += b_out
  }
}

// ------------- input MFMA GEMM: U[:,0:128] = bf16(x @ W_in + b_in) ---------
// Round-9 rewrite: T3-lite 2-phase pipeline with global_load_lds (width 16).
//  - 32x128 tile (grid 1563), BK=64, 4 waves; wave = 16 rows x 64 cols.
//  - A staged as fp32, B as bf16, both via global_load_lds into LINEAR LDS
//    with the XOR-swizzle applied on the per-lane GLOBAL source address
//    (rule #21: linear dest + inverse-swz source + swz read). A uses a 32B-
//    granular XOR (frag = 8 consecutive floats), B a 16B-granular XOR.
//  - Double-buffered LDS (48 KB -> 3 blocks/CU), counted s_waitcnt vmcnt(6)
//    + raw s_barrier: the next tile's 6 loads stay in flight across the
//    barrier while the current tile computes. NO __syncthreads() in the
//    k-loop (it drains vmcnt(0) and serializes memory, the old ~65us cause).
//  - A fp32->bf16 conversion happens at fragment-read time (VALU was 6% busy).
//  - Zero staging registers -> no spill pressure; waves_per_eu(3,4) keeps RA
//    budget ~128 VGPR (spills would be scratch VMEM ops and corrupt the
//    vmcnt count).
__global__ __launch_bounds__(256)
__attribute__((amdgpu_waves_per_eu(3, 4)))
void mfma_gemm_in_k(
    const float* __restrict__ A, const unsigned short* __restrict__ Wt,
    const float* __restrict__ bias, unsigned short* __restrict__ C, int M) {
  constexpr int K = F_IN, BK = 64, NT = K / BK;   // 8 k-stages
  __shared__ __align__(16) float As[2][32][64];          // 16 KB
  __shared__ __align__(16) unsigned short Bs[2][128][64]; // 32 KB
  const int t = threadIdx.x;
  const int lane = t & 63;
  const int w = t >> 6;
  const int q = lane >> 4;
  const int l15 = lane & 15;
  const int wm = w >> 1, wn = w & 1;
  const int m0 = blockIdx.x * 32;

  // ---- per-lane pre-swizzled global source pointers ----
  // A: inst it in {0,1}: LDS rows r = it*16 + w*4 + (lane>>4), chunk16 = lane&15.
  // LDS 32B pair-chunk p of row r holds global pair-chunk p ^ (r&7).
  const float* pA[2];
#pragma unroll
  for (int it = 0; it < 2; ++it) {
    int r = it * 16 + w * 4 + (lane >> 4);
    int gm = m0 + r; if (gm >= M) gm = M - 1;
    int c16 = lane & 15;
    int gcol = ((((c16 >> 1) ^ (r & 7)) << 3)) + ((c16 & 1) << 2);
    pA[it] = A + (size_t)gm * K + gcol;
  }
  // B: inst it in {0..3}: LDS rows r = (it*4 + w)*8 + (lane>>3), chunk16 = lane&7.
  // LDS 16B chunk c of row r holds global chunk c ^ (r&7).
  const unsigned short* pB[4];
#pragma unroll
  for (int it = 0; it < 4; ++it) {
    int r = (it * 4 + w) * 8 + (lane >> 3);
    int c = lane & 7;
    pB[it] = Wt + (size_t)r * K + ((c ^ (r & 7)) << 3);
  }

  f32x4 acc[4];
#pragma unroll
  for (int j = 0; j < 4; ++j) acc[j] = (f32x4){0.f, 0.f, 0.f, 0.f};

  // stage ks into LDS buffer buf: 2 A-insts + 4 B-insts per thread = 6 VMEM/wave
  auto STAGE = [&](int buf, int ks) {
#pragma unroll
    for (int it = 0; it < 2; ++it)
      GLOAD_LDS16(pA[it] + ks * BK, &As[buf][it * 16 + w * 4][0] + lane * 4);
#pragma unroll
    for (int it = 0; it < 4; ++it)
      GLOAD_LDS16(pB[it] + ks * BK, &Bs[buf][(it * 4 + w) * 8][0] + lane * 8);
  };

  auto COMPUTE = [&](int buf) {
#pragma unroll
    for (int kk = 0; kk < 2; ++kk) {
      int kc = (kk << 2) + q;
      int m = (wm << 4) + l15;
      const float* ap = &As[buf][m][(kc ^ (m & 7)) << 3];
      float4 f0 = *(const float4*)ap;
      float4 f1 = *(const float4*)(ap + 4);
      union { unsigned int u[4]; bf16x8 v; } ua;
      ua.u[0] = (unsigned int)bf16_rne(f0.x) | ((unsigned int)bf16_rne(f0.y) << 16);
      ua.u[1] = (unsigned int)bf16_rne(f0.z) | ((unsigned int)bf16_rne(f0.w) << 16);
      ua.u[2] = (unsigned int)bf16_rne(f1.x) | ((unsigned int)bf16_rne(f1.y) << 16);
      ua.u[3] = (unsigned int)bf16_rne(f1.z) | ((unsigned int)bf16_rne(f1.w) << 16);
      bf16x8 af = ua.v;
#pragma unroll
      for (int j = 0; j < 4; ++j) {
        int nn = (wn << 6) + (j << 4) + l15;
        bf16x8 bfr = *(const bf16x8*)&Bs[buf][nn][(kc ^ (nn & 7)) << 3];
        acc[j] = __builtin_amdgcn_mfma_f32_16x16x32_bf16(af, bfr, acc[j], 0, 0, 0);
      }
    }
  };

  STAGE(0, 0);
#pragma unroll
  for (int ts = 0; ts < NT; ++ts) {
    if (ts + 1 < NT) {
      STAGE((ts + 1) & 1, ts + 1);                       // 6 more in flight (12)
      asm volatile("s_waitcnt vmcnt(6)" ::: "memory");   // stage ts landed
    } else {
      asm volatile("s_waitcnt vmcnt(0)" ::: "memory");   // drain last stage
    }
    __builtin_amdgcn_s_barrier();
    __builtin_amdgcn_sched_barrier(0);   // no ds_read hoists above the barrier
    COMPUTE(ts & 1);
    __builtin_amdgcn_sched_barrier(0);
    __builtin_amdgcn_s_barrier();        // compute done before buf reuse
  }

#pragma unroll
  for (int j = 0; j < 4; ++j) {
    int col = (wn << 6) + (j << 4) + l15;
    float bv = bias[col];
    int rb = m0 + (wm << 4) + (q << 2);
#pragma unroll
    for (int r = 0; r < 4; ++r) {
      int row = rb + r;
      if (row < M) C[(size_t)row * KTOT + col] = bf16_rne(acc[j][r] + bv);
    }
  }
}

// ------------- aggregation: U[:,out] = A * U[:,in]; scalar chain -----------
// SMODE 0: none; 1: sout = sum w (d = A*1); 2: sout = sum w*sprev[src]
// 8-edge unroll: 8 outstanding 256B row-gathers per wave (round-9: was 4 —
// gather is L3-latency exposed; accumulation grouping kept in 4s so the FP
// sum order is bit-identical to the 4-unroll version).
template <int SMODE>
__global__ __launch_bounds__(256) void agg_k(
    const int* __restrict__ rowp, const int2* __restrict__ csr,
    unsigned int* __restrict__ U32, int co_in, int co_out,
    const float* __restrict__ sprev, float* __restrict__ sout, int n) {
  const int lane = threadIdx.x & 63;
  const int node = (blockIdx.x << 2) + (threadIdx.x >> 6);
  if (node >= n) return;
  const int RS = KTOT / 2;   // 320 uints per row
  int beg = rowp[node], end = rowp[node + 1];
  float ax = 0.f, ay = 0.f, sacc = 0.f;
  const unsigned int* in = U32 + co_in + lane;
  int j = beg;
  for (; j + 7 < end; j += 8) {
    int2 e0 = csr[j],     e1 = csr[j + 1], e2 = csr[j + 2], e3 = csr[j + 3];
    int2 e4 = csr[j + 4], e5 = csr[j + 5], e6 = csr[j + 6], e7 = csr[j + 7];
    unsigned int v0 = in[(size_t)e0.x * RS];
    unsigned int v1 = in[(size_t)e1.x * RS];
    unsigned int v2 = in[(size_t)e2.x * RS];
    unsigned int v3 = in[(size_t)e3.x * RS];
    unsigned int v4 = in[(size_t)e4.x * RS];
    unsigned int v5 = in[(size_t)e5.x * RS];
    unsigned int v6 = in[(size_t)e6.x * RS];
    unsigned int v7 = in[(size_t)e7.x * RS];
    float w0 = __int_as_float(e0.y), w1 = __int_as_float(e1.y);
    float w2 = __int_as_float(e2.y), w3 = __int_as_float(e3.y);
    float w4 = __int_as_float(e4.y), w5 = __int_as_float(e5.y);
    float w6 = __int_as_float(e6.y), w7 = __int_as_float(e7.y);
    ax += w0 * bf16_lo_f(v0) + w1 * bf16_lo_f(v1) +
          w2 * bf16_lo_f(v2) + w3 * bf16_lo_f(v3);
    ay += w0 * bf16_hi_f(v0) + w1 * bf16_hi_f(v1) +
          w2 * bf16_hi_f(v2) + w3 * bf16_hi_f(v3);
    ax += w4 * bf16_lo_f(v4) + w5 * bf16_lo_f(v5) +
          w6 * bf16_lo_f(v6) + w7 * bf16_lo_f(v7);
    ay += w4 * bf16_hi_f(v4) + w5 * bf16_hi_f(v5) +
          w6 * bf16_hi_f(v6) + w7 * bf16_hi_f(v7);
    if (SMODE == 1) { sacc += (w0 + w1) + (w2 + w3); sacc += (w4 + w5) + (w6 + w7); }
    if (SMODE == 2) {
      sacc += w0 * sprev[e0.x] + w1 * sprev[e1.x] +
              w2 * sprev[e2.x] + w3 * sprev[e3.x];
      sacc += w4 * sprev[e4.x] + w5 * sprev[e5.x] +
              w6 * sprev[e6.x] + w7 * sprev[e7.x];
    }
  }
  for (; j + 3 < end; j += 4) {
    int2 e0 = csr[j], e1 = csr[j + 1], e2 = csr[j + 2], e3 = csr[j + 3];
    unsigned int v0 = in[(size_t)e0.x * RS];
    unsigned int v1 = in[(size_t)e1.x * RS];
    unsigned int v2 = in[(size_t)e2.x * RS];
    unsigned int v3 = in[(size_t)e3.x * RS];
    float w0 = __int_as_float(e0.y), w1 = __int_as_float(e1.y);
    float w2 = __int_as_float(e2.y), w3 = __int_as_float(e3.y);
    ax += w0 * bf16_lo_f(v0) + w1 * bf16_lo_f(v1) +
          w2 * bf16_lo_f(v2) + w3 * bf16_lo_f(v3);
    ay += w0 * bf16_hi_f(v0) + w1 * bf16_hi_f(v1) +
          w2 * bf16_hi_f(v2) + w3 * bf16_hi_f(v3);
    if (SMODE == 1) sacc += (w0 + w1) + (w2 + w3);
    if (SMODE == 2) sacc += w0 * sprev[e0.x] + w1 * sprev[e1.x] +
                            w2 * sprev[e2.x] + w3 * sprev[e3.x];
  }
  for (; j < end; ++j) {
    int2 e0 = csr[j];
    float w0 = __int_as_float(e0.y);
    unsigned int v0 = in[(size_t)e0.x * RS];
    ax += w0 * bf16_lo_f(v0);
    ay += w0 * bf16_hi_f(v0);
    if (SMODE == 1) sacc += w0;
    if (SMODE == 2) sacc += w0 * sprev[e0.x];
  }
  U32[(size_t)node * RS + co_out + lane] =
      (unsigned int)bf16_rne(ax) | ((unsigned int)bf16_rne(ay) << 16);
  if (SMODE != 0 && lane == 0) sout[node] = sacc;
}

// ------ final fused GEMM: out = U[M,640] @ P[640,40] + rank-1 terms --------
__global__ __launch_bounds__(256) void final_gemm_k(
    const unsigned short* __restrict__ U, const unsigned short* __restrict__ Pbf,
    const float* __restrict__ dvec, const float* __restrict__ evec,
    const float* __restrict__ fvec, const float* __restrict__ rv,
    float* __restrict__ out, int M) {
  constexpr int K = KTOT, BK = 64;
  __shared__ __align__(16) unsigned short As[128][BK];
  __shared__ __align__(16) unsigned short Bs[NPAD][BK];
  const int t = threadIdx.x;
  const int lane = t & 63;
  const int q = lane >> 4;
  const int l15 = lane & 15;
  const int w = t >> 6;
  const int m0 = blockIdx.x * 128;

  f32x4 acc[2][3];
#pragma unroll
  for (int i = 0; i < 2; ++i)
#pragma unroll
    for (int j = 0; j < 3; ++j) acc[i][j] = (f32x4){0.f, 0.f, 0.f, 0.f};

  for (int k0 = 0; k0 < K; k0 += BK) {
#pragma unroll
    for (int it = 0; it < 4; ++it) {
      int id = t + it * 256;
      int r = id >> 3, kc = id & 7;
      int gm = m0 + r; if (gm >= M) gm = M - 1;
      uint4 v = *(const uint4*)&U[(size_t)gm * K + k0 + (kc << 3)];
      *(uint4*)&As[r][(kc ^ (r & 7)) << 3] = v;
    }
    for (int id = t; id < NPAD * 8; id += 256) {
      int nn = id >> 3, kc = id & 7;
      uint4 v = *(const uint4*)&Pbf[(size_t)nn * K + k0 + (kc << 3)];
      *(uint4*)&Bs[nn][(kc ^ (nn & 7)) << 3] = v;
    }
    __syncthreads();
#pragma unroll
    for (int kk = 0; kk < 2; ++kk) {
      bf16x8 af[2], bfr[3];
      int kc = (kk << 2) + q;
#pragma unroll
      for (int i = 0; i < 2; ++i) {
        int m = (w << 5) + (i << 4) + l15;
        af[i] = *(const bf16x8*)&As[m][(kc ^ (m & 7)) << 3];
      }
#pragma unroll
      for (int j = 0; j < 3; ++j) {
        int nn = (j << 4) + l15;
        bfr[j] = *(const bf16x8*)&Bs[nn][(kc ^ (nn & 7)) << 3];
      }
#pragma unroll
      for (int i = 0; i < 2; ++i)
#pragma unroll
        for (int j = 0; j < 3; ++j)
          acc[i][j] = __builtin_amdgcn_mfma_f32_16x16x32_bf16(af[i], bfr[j], acc[i][j], 0, 0, 0);
    }
    __syncthreads();
  }
#pragma unroll
  for (int j = 0; j < 3; ++j) {
    int col = (j << 4) + l15;
    if (col >= C_OUT) continue;
    float r1 = rv[0 * 40 + col], rd = rv[1 * 40 + col];
    float re = rv[2 * 40 + col], rf = rv[3 * 40 + col];
#pragma unroll
    for (int i = 0; i < 2; ++i) {
      int rb = m0 + (w << 5) + (i << 4) + (q << 2);
#pragma unroll
      for (int r = 0; r < 4; ++r) {
        int row = rb + r;
        if (row < M) {
          float v = acc[i][j][r] + r1 +
                    dvec[row] * rd + evec[row] * re + fvec[row] * rf;
          out[(size_t)row * C_OUT + col] = v;
        }
      }
    }
  }
}

// ------------------------------- launcher ----------------------------------

extern "C" void kernel_launch(void* const* d_in, const int* in_sizes, int n_in,
                              void* d_out, int out_size, void* d_ws, size_t ws_size,
                              hipStream_t stream) {
  const float* x     = (const float*)d_in[0];
  const int*   eidx  = (const int*)  d_in[1];
  const float* ew    = (const float*)d_in[2];
  const float* W_in  = (const float*)d_in[3];
  const float* b_in  = (const float*)d_in[4];
  const float* W_gcn = (const float*)d_in[5];
  const float* b_gcn = (const float*)d_in[6];
  const float* W_out = (const float*)d_in[7];
  const float* b_out = (const float*)d_in[8];
  float* out = (float*)d_out;

  const int* src = eidx;
  const int* dst = eidx + N_EDGES;

  char* ws = (char*)d_ws;
  size_t off = 0;
  auto alloc = [&](size_t bytes) -> void* {
    void* p = ws + off;
    off += (bytes + 255) & ~(size_t)255;
    return p;
  };
  unsigned long long* acc = (unsigned long long*)alloc((size_t)N_NODES * 8);
  int*   pos    = (int*)  alloc((size_t)N_EDGES * 4);
  int*   cnt    = (int*)  alloc((size_t)N_NODES * 4);
  int*   rowp   = (int*)  alloc((size_t)(N_NODES + 1) * 4);
  float* dinv   = (float*)alloc((size_t)N_NODES * 4);
  int*   bsum   = (int*)  alloc((size_t)256 * 4);
  int2*  csr    = (int2*) alloc((size_t)TOT_E * 8);
  unsigned short* Wt_in = (unsigned short*)alloc((size_t)F_IN * H_DIM * 2);
  unsigned short* Pbf   = (unsigned short*)alloc((size_t)NPAD * KTOT * 2);
  unsigned short* U     = (unsigned short*)alloc((size_t)N_NODES * KTOT * 2);
  float* dvec   = (float*)alloc((size_t)N_NODES * 4);
  float* evec   = (float*)alloc((size_t)N_NODES * 4);
  float* fvec   = (float*)alloc((size_t)N_NODES * 4);
  float* rv     = (float*)alloc((size_t)4 * 40 * 4);
  (void)ws_size; (void)in_sizes; (void)n_in; (void)out_size;

  dim3 b256(256);
  const int NB = (N_NODES + 255) / 256;
  const int GB32 = (N_NODES + 31) / 32;     // 1563 blocks for input GEMM
  const int GB = (N_NODES + 127) / 128;     // 391 blocks for final GEMM
  const int AB = (N_NODES + 3) / 4;
  unsigned int* U32 = (unsigned int*)U;

  hipMemsetAsync(acc, 0, (size_t)N_NODES * 8, stream);
  hipMemsetAsync(rv, 0, (size_t)4 * 40 * 4, stream);
  hipMemsetAsync(Pbf, 0, (size_t)NPAD * KTOT * 2, stream);  // pad cols 40..47 = 0

  edge_pass1_k<<<(N_EDGES + 255) / 256, b256, 0, stream>>>(dst, ew, acc, pos, N_EDGES);
  node_pass_k<<<NB, b256, 0, stream>>>(acc, dinv, cnt, N_NODES);
  block_reduce_k<<<NB, b256, 0, stream>>>(cnt, bsum, N_NODES);
  scan_bsums_k<<<1, b256, 0, stream>>>(bsum, NB);
  scan_write_k<<<NB, b256, 0, stream>>>(cnt, bsum, rowp, N_NODES);
  scatter2_k<<<(TOT_E + 255) / 256, b256, 0, stream>>>(src, dst, ew, pos, dinv, rowp,
                                                       csr, N_EDGES, N_NODES);

  wcast_k<<<(F_IN * H_DIM + 255) / 256, b256, 0, stream>>>(W_in, Wt_in, F_IN, F_IN * H_DIM);
  chains_k<<<dim3(10, 4), b256, 0, stream>>>(W_gcn, b_gcn, W_out, b_out, Pbf, rv);

  // U[:,0:128] = bf16(x @ W_in + b_in)
  mfma_gemm_in_k<<<GB32, b256, 0, stream>>>(x, Wt_in, b_in, U, N_NODES);

  // u-chain: u_{p} = A * u_{p-1}; scalar chain d = A*1, e = A*d, f = A*e
  agg_k<1><<<AB, b256, 0, stream>>>(rowp, csr, U32, 0,   64,  nullptr, dvec, N_NODES);
  agg_k<2><<<AB, b256, 0, stream>>>(rowp, csr, U32, 64,  128, dvec,    evec, N_NODES);
  agg_k<2><<<AB, b256, 0, stream>>>(rowp, csr, U32, 128, 192, evec,    fvec, N_NODES);
  agg_k<0><<<AB, b256, 0, stream>>>(rowp, csr, U32, 192, 256, nullptr, nullptr, N_NODES);

  final_gemm_k<<<GB, b256, 0, stream>>>(U, Pbf, dvec, evec, fvec, rv, out, N_NODES);
}